// Round 6
// baseline (1023.170 us; speedup 1.0000x reference)
//
#include <hip/hip_runtime.h>
#include <math.h>

#define D_ 128
#define H_ 160
#define W_ 160
#define NVOX (D_*H_*W_)
#define HW (H_*W_)
#define N4 (NVOX/4)

// Gaussian kernel, sigma=1, radius=2, normalized
#define K0 0.40261996f
#define K1 0.24420134f
#define K2 0.05448868f

union F4 { float4 v; float a[4]; };

__device__ __forceinline__ float4 zero4() { float4 z; z.x=z.y=z.z=z.w=0.f; return z; }

__device__ __forceinline__ float fetch_mov(const float* __restrict__ m, int d, int h, int w) {
    if ((unsigned)d >= (unsigned)D_ || (unsigned)h >= (unsigned)H_ || (unsigned)w >= (unsigned)W_) return 0.0f;
    return m[(size_t)(d*H_ + h)*W_ + w];
}

__device__ __forceinline__ float trilerp(const float* __restrict__ mov,
                                         float cd, float ch, float cw) {
    float fd = floorf(cd), fh = floorf(ch), fw = floorf(cw);
    int di = (int)fd, hi = (int)fh, wi = (int)fw;
    float td = cd - fd, th = ch - fh, tw = cw - fw;
    float c000, c001, c010, c011, c100, c101, c110, c111;
    if (di >= 0 && di < D_-1 && hi >= 0 && hi < H_-1 && wi >= 0 && wi < W_-1) {
        const float* p = mov + (size_t)di*HW + hi*W_ + wi;
        c000 = p[0];    c001 = p[1];
        c010 = p[W_];   c011 = p[W_+1];
        const float* q = p + HW;
        c100 = q[0];    c101 = q[1];
        c110 = q[W_];   c111 = q[W_+1];
    } else {
        c000 = fetch_mov(mov, di,   hi,   wi  );
        c001 = fetch_mov(mov, di,   hi,   wi+1);
        c010 = fetch_mov(mov, di,   hi+1, wi  );
        c011 = fetch_mov(mov, di,   hi+1, wi+1);
        c100 = fetch_mov(mov, di+1, hi,   wi  );
        c101 = fetch_mov(mov, di+1, hi,   wi+1);
        c110 = fetch_mov(mov, di+1, hi+1, wi  );
        c111 = fetch_mov(mov, di+1, hi+1, wi+1);
    }
    float c00 = c000 + tw*(c001 - c000);
    float c01 = c010 + tw*(c011 - c010);
    float c10 = c100 + tw*(c101 - c100);
    float c11 = c110 + tw*(c111 - c110);
    float c0 = c00 + th*(c01 - c00);
    float c1 = c10 + th*(c11 - c10);
    return c0 + td*(c1 - c0);
}

// ---------------------------------------------------------------------------
// demon force: uvf = vf + scale * (grad(warped) + grad(fix)), gfix recomputed
// on the fly from the fix stencil. zero_vf=1 treats vf as 0 (iteration 0).
// ---------------------------------------------------------------------------
__global__ __launch_bounds__(256) void force_kernel(const float* __restrict__ warped,
                                                    const float* __restrict__ fix,
                                                    const float* __restrict__ vf,
                                                    float* __restrict__ out,
                                                    int zero_vf) {
    int i4 = blockIdx.x*blockDim.x + threadIdx.x;
    if (i4 >= N4) return;
    int base = 4*i4;
    int w = base % W_;
    int h = (base / W_) % H_;
    int d = base / HW;
    const float4* w4p = (const float4*)warped;
    const float4* f4p = (const float4*)fix;
    F4 c;  c.v  = w4p[i4];
    F4 fc; fc.v = f4p[i4];
    float cl = (w > 0)     ? warped[base-1] : 0.f;
    float cr = (w+4 < W_)  ? warped[base+4] : 0.f;
    float fl = (w > 0)     ? fix[base-1] : 0.f;
    float fr = (w+4 < W_)  ? fix[base+4] : 0.f;
    // edge trick: replacing the missing neighbor with the center turns the
    // central difference (scale 1 at edges) into the one-sided difference.
    F4 hu;  hu.v  = (h < H_-1) ? w4p[i4 + W_/4] : c.v;
    F4 hd;  hd.v  = (h > 0)    ? w4p[i4 - W_/4] : c.v;
    F4 du;  du.v  = (d < D_-1) ? w4p[i4 + HW/4] : c.v;
    F4 dn;  dn.v  = (d > 0)    ? w4p[i4 - HW/4] : c.v;
    F4 fhu; fhu.v = (h < H_-1) ? f4p[i4 + W_/4] : fc.v;
    F4 fhd; fhd.v = (h > 0)    ? f4p[i4 - W_/4] : fc.v;
    F4 fdu; fdu.v = (d < D_-1) ? f4p[i4 + HW/4] : fc.v;
    F4 fdn; fdn.v = (d > 0)    ? f4p[i4 - HW/4] : fc.v;
    float hs  = (h==0 || h==H_-1) ? 1.f : 0.5f;
    float dsc = (d==0 || d==D_-1) ? 1.f : 0.5f;
    F4 v0, v1, v2;
    if (zero_vf) {
        v0.v = zero4(); v1.v = zero4(); v2.v = zero4();
    } else {
        v0.v = ((const float4*)vf)[i4];
        v1.v = ((const float4*)vf)[i4 + N4];
        v2.v = ((const float4*)vf)[i4 + 2*N4];
    }
    float m [6] = {cl, c.a[0],  c.a[1],  c.a[2],  c.a[3],  cr};
    float fm[6] = {fl, fc.a[0], fc.a[1], fc.a[2], fc.a[3], fr};
    #pragma unroll
    for (int j = 0; j < 4; ++j) {
        int wj = w + j;
        float wsc  = (wj == 0 || wj == W_-1) ? 1.f : 0.5f;
        float prev  = (wj == 0)    ? m[1]  : m[j];
        float next  = (wj == W_-1) ? m[4]  : m[j+2];
        float fprev = (wj == 0)    ? fm[1] : fm[j];
        float fnext = (wj == W_-1) ? fm[4] : fm[j+2];
        float gwv = wsc*(next - prev);
        float ghv = hs *(hu.a[j] - hd.a[j]);
        float gdv = dsc*(du.a[j] - dn.a[j]);
        float fgw = wsc*(fnext - fprev);
        float fgh = hs *(fhu.a[j] - fhd.a[j]);
        float fgd = dsc*(fdu.a[j] - fdn.a[j]);
        float diff = c.a[j] - fc.a[j];
        float G0 = gdv + fgd;
        float G1 = ghv + fgh;
        float G2 = gwv + fgw;
        float denom = G0*G0 + G1*G1 + G2*G2 + diff*diff;
        float scale = (denom > 1e-6f) ? (-diff/denom) : 0.0f;
        v0.a[j] += scale*G0;
        v1.a[j] += scale*G1;
        v2.a[j] += scale*G2;
    }
    ((float4*)out)[i4]        = v0.v;
    ((float4*)out)[i4 + N4]   = v1.v;
    ((float4*)out)[i4 + 2*N4] = v2.v;
}

// ---------------------------------------------------------------------------
// Fused separable 3D Gaussian over all 3 channels + immediate warp of the
// smoothed field. Block (8,32) = 256 threads; 32x32 (W,H) tile; D streamed.
// SCHUNK=4 -> grid (5,5,32) = 800 blocks: occupancy was the round-5 limiter
// (400 blocks = 12.5%); trade D-halo traffic (1.5x -> 2.0x) for 2x waves.
// ---------------------------------------------------------------------------
#define SCHUNK 4

__global__ __launch_bounds__(256) void smooth_warp_kernel(const float* __restrict__ src,
                                                          const float* __restrict__ mov,
                                                          float* __restrict__ vf_out,
                                                          float* __restrict__ warped_out,
                                                          int do_warp) {
    __shared__ float raw[3][36][40];  // input slice, rows h0-2..h0+33, cols w0-4..w0+35
    __shared__ float s1[3][36][40];   // after W-conv; cols 0..31 used
    const int tx = threadIdx.x;       // 0..7  (float4 col)
    const int ty = threadIdx.y;       // 0..31 (row)
    const int tid = ty*8 + tx;
    const int w0 = blockIdx.x * 32;
    const int h0 = blockIdx.y * 32;
    const int d0 = blockIdx.z * SCHUNK;

    // staging geometry: per channel 360 float4 slots (36 rows x 10 cols)
    const int tB = tid + 256;
    const int rA = tid/10, cA = tid%10;
    const int rB = tB/10,  cB = tB%10;
    const bool hasB = (tB < 360);
    const int ghA = h0-2+rA, gwA = w0-4+4*cA;
    const int ghB = h0-2+rB, gwB = w0-4+4*cB;
    const bool bA = (unsigned)ghA < (unsigned)H_ && (unsigned)gwA < (unsigned)W_;
    const bool bB = hasB && (unsigned)ghB < (unsigned)H_ && (unsigned)gwB < (unsigned)W_;
    const int oA = ghA*W_ + gwA;
    const int oB = ghB*W_ + gwB;

    float4 pA[3], pB[3];
    {
        int dd = d0-2;
        #pragma unroll
        for (int ch = 0; ch < 3; ++ch) { pA[ch] = zero4(); pB[ch] = zero4(); }
        if ((unsigned)dd < (unsigned)D_) {
            #pragma unroll
            for (int ch = 0; ch < 3; ++ch) {
                const float* sp = src + (size_t)ch*NVOX + (size_t)dd*HW;
                if (bA) pA[ch] = *(const float4*)(sp + oA);
                if (bB) pB[ch] = *(const float4*)(sp + oB);
            }
        }
    }

    float4 wn[3][5];
    #pragma unroll
    for (int ch = 0; ch < 3; ++ch)
        #pragma unroll
        for (int k = 0; k < 5; ++k) wn[ch][k] = zero4();

    for (int dd = d0-2; dd < d0+SCHUNK+2; ++dd) {
        // store staged plane
        #pragma unroll
        for (int ch = 0; ch < 3; ++ch) {
            *(float4*)&raw[ch][rA][4*cA] = pA[ch];
            if (hasB) *(float4*)&raw[ch][rB][4*cB] = pB[ch];
        }
        // prefetch next plane (latency overlaps conv + barriers)
        #pragma unroll
        for (int ch = 0; ch < 3; ++ch) { pA[ch] = zero4(); pB[ch] = zero4(); }
        int dn2 = dd + 1;
        if (dn2 < d0+SCHUNK+2 && (unsigned)dn2 < (unsigned)D_) {
            #pragma unroll
            for (int ch = 0; ch < 3; ++ch) {
                const float* sp = src + (size_t)ch*NVOX + (size_t)dn2*HW;
                if (bA) pA[ch] = *(const float4*)(sp + oA);
                if (bB) pB[ch] = *(const float4*)(sp + oB);
            }
        }
        __syncthreads();
        // W-conv: 3ch x 36 rows x 8 out-f4 = 864 tasks
        for (int t = tid; t < 864; t += 256) {
            int ch = t / 288, rem = t % 288;
            int r = rem / 8, k = rem % 8;
            const float* rp = &raw[ch][r][0];
            F4 a, b, cc;
            a.v  = *(const float4*)(rp + 4*k);
            b.v  = *(const float4*)(rp + 4*k + 4);
            cc.v = *(const float4*)(rp + 4*k + 8);
            float mm[12];
            #pragma unroll
            for (int j = 0; j < 4; ++j) { mm[j]=a.a[j]; mm[4+j]=b.a[j]; mm[8+j]=cc.a[j]; }
            F4 o4;
            #pragma unroll
            for (int j = 0; j < 4; ++j)
                o4.a[j] = K2*(mm[j+2]+mm[j+6]) + K1*(mm[j+3]+mm[j+5]) + K0*mm[j+4];
            *(float4*)&s1[ch][r][4*k] = o4.v;
        }
        __syncthreads();
        // H-conv + D rolling window per channel
        #pragma unroll
        for (int ch = 0; ch < 3; ++ch) {
            float4 q0 = *(const float4*)&s1[ch][ty  ][4*tx];
            float4 q1 = *(const float4*)&s1[ch][ty+1][4*tx];
            float4 q2 = *(const float4*)&s1[ch][ty+2][4*tx];
            float4 q3 = *(const float4*)&s1[ch][ty+3][4*tx];
            float4 q4 = *(const float4*)&s1[ch][ty+4][4*tx];
            float4 s2;
            s2.x = K2*(q0.x+q4.x) + K1*(q1.x+q3.x) + K0*q2.x;
            s2.y = K2*(q0.y+q4.y) + K1*(q1.y+q3.y) + K0*q2.y;
            s2.z = K2*(q0.z+q4.z) + K1*(q1.z+q3.z) + K0*q2.z;
            s2.w = K2*(q0.w+q4.w) + K1*(q1.w+q3.w) + K0*q2.w;
            wn[ch][0]=wn[ch][1]; wn[ch][1]=wn[ch][2]; wn[ch][2]=wn[ch][3]; wn[ch][3]=wn[ch][4]; wn[ch][4]=s2;
        }
        int od = dd - 2;
        if (od >= d0) {
            F4 va[3];
            #pragma unroll
            for (int ch = 0; ch < 3; ++ch) {
                va[ch].a[0] = K2*(wn[ch][0].x+wn[ch][4].x) + K1*(wn[ch][1].x+wn[ch][3].x) + K0*wn[ch][2].x;
                va[ch].a[1] = K2*(wn[ch][0].y+wn[ch][4].y) + K1*(wn[ch][1].y+wn[ch][3].y) + K0*wn[ch][2].y;
                va[ch].a[2] = K2*(wn[ch][0].z+wn[ch][4].z) + K1*(wn[ch][1].z+wn[ch][3].z) + K0*wn[ch][2].z;
                va[ch].a[3] = K2*(wn[ch][0].w+wn[ch][4].w) + K1*(wn[ch][1].w+wn[ch][3].w) + K0*wn[ch][2].w;
            }
            size_t base = (size_t)od*HW + (h0+ty)*W_ + w0 + 4*tx;
            *(float4*)(vf_out + base)          = va[0].v;
            *(float4*)(vf_out + NVOX + base)   = va[1].v;
            *(float4*)(vf_out + 2*NVOX + base) = va[2].v;
            if (do_warp) {
                F4 r4o;
                #pragma unroll
                for (int j = 0; j < 4; ++j) {
                    float cd = (float)od          + va[0].a[j];
                    float chh = (float)(h0+ty)    + va[1].a[j];
                    float cw = (float)(w0+4*tx+j) + va[2].a[j];
                    r4o.a[j] = trilerp(mov, cd, chh, cw);
                }
                *(float4*)(warped_out + base) = r4o.v;
            }
        }
    }
}

extern "C" void kernel_launch(void* const* d_in, const int* in_sizes, int n_in,
                              void* d_out, int out_size, void* d_ws, size_t ws_size,
                              hipStream_t stream) {
    const float* mov = (const float*)d_in[0];
    const float* fix = (const float*)d_in[1];
    const int ITERS = 10;

    float* ws     = (float*)d_ws;
    float* vfA    = ws;                       // 3N — the vf state
    float* uvf    = ws + (size_t)3*NVOX;      // 3N — force output
    float* warped = ws + (size_t)6*NVOX;      // N

    const int nb4 = (N4 + 255)/256;
    dim3 sg(W_/32, H_/32, D_/SCHUNK);
    dim3 sb(8, 32);

    for (int it = 0; it < ITERS; ++it) {
        // it==0: vf == 0 => warped == mov exactly (integer-coordinate trilerp)
        const float* wsrc = (it == 0) ? mov : warped;
        force_kernel<<<nb4, 256, 0, stream>>>(wsrc, fix, vfA, uvf, it == 0 ? 1 : 0);
        float* vdst = (it == ITERS-1) ? (float*)d_out : vfA;
        smooth_warp_kernel<<<sg, sb, 0, stream>>>(uvf, mov, vdst, warped,
                                                  it == ITERS-1 ? 0 : 1);
    }
}

// Round 7
// 976.555 us; speedup vs baseline: 1.0477x; 1.0477x over previous
//
#include <hip/hip_runtime.h>
#include <math.h>

#define D_ 128
#define H_ 160
#define W_ 160
#define NVOX (D_*H_*W_)
#define HW (H_*W_)
#define N4 (NVOX/4)

// Gaussian kernel, sigma=1, radius=2, normalized
#define K0 0.40261996f
#define K1 0.24420134f
#define K2 0.05448868f

union F4 { float4 v; float a[4]; };

__device__ __forceinline__ float4 zero4() { float4 z; z.x=z.y=z.z=z.w=0.f; return z; }

__device__ __forceinline__ float fetch_mov(const float* __restrict__ m, int d, int h, int w) {
    if ((unsigned)d >= (unsigned)D_ || (unsigned)h >= (unsigned)H_ || (unsigned)w >= (unsigned)W_) return 0.0f;
    return m[(size_t)(d*H_ + h)*W_ + w];
}

__device__ __forceinline__ float trilerp(const float* __restrict__ mov,
                                         float cd, float ch, float cw) {
    float fd = floorf(cd), fh = floorf(ch), fw = floorf(cw);
    int di = (int)fd, hi = (int)fh, wi = (int)fw;
    float td = cd - fd, th = ch - fh, tw = cw - fw;
    float c000, c001, c010, c011, c100, c101, c110, c111;
    if (di >= 0 && di < D_-1 && hi >= 0 && hi < H_-1 && wi >= 0 && wi < W_-1) {
        const float* p = mov + (size_t)di*HW + hi*W_ + wi;
        c000 = p[0];    c001 = p[1];
        c010 = p[W_];   c011 = p[W_+1];
        const float* q = p + HW;
        c100 = q[0];    c101 = q[1];
        c110 = q[W_];   c111 = q[W_+1];
    } else {
        c000 = fetch_mov(mov, di,   hi,   wi  );
        c001 = fetch_mov(mov, di,   hi,   wi+1);
        c010 = fetch_mov(mov, di,   hi+1, wi  );
        c011 = fetch_mov(mov, di,   hi+1, wi+1);
        c100 = fetch_mov(mov, di+1, hi,   wi  );
        c101 = fetch_mov(mov, di+1, hi,   wi+1);
        c110 = fetch_mov(mov, di+1, hi+1, wi  );
        c111 = fetch_mov(mov, di+1, hi+1, wi+1);
    }
    float c00 = c000 + tw*(c001 - c000);
    float c01 = c010 + tw*(c011 - c010);
    float c10 = c100 + tw*(c101 - c100);
    float c11 = c110 + tw*(c111 - c110);
    float c0 = c00 + th*(c01 - c00);
    float c1 = c10 + th*(c11 - c10);
    return c0 + td*(c1 - c0);
}

// demons force at an aligned float4 (d, gh, gw..gw+3), all inside the volume.
// Edge rule: substituting the center for a missing d/h neighbor turns the
// 0.5x central difference into the 1x one-sided difference (with hs/ds=1).
__device__ __forceinline__ void force_f4(const float* __restrict__ warped,
                                         const float* __restrict__ fix,
                                         const float* __restrict__ vf,
                                         int zero_vf, int d, int gh, int gw,
                                         F4& o0, F4& o1, F4& o2) {
    size_t base = (size_t)d*HW + gh*W_ + gw;
    int i4 = (int)(base >> 2);
    const float4* w4p = (const float4*)warped;
    const float4* f4p = (const float4*)fix;
    F4 c;  c.v  = w4p[i4];
    F4 fc; fc.v = f4p[i4];
    float cl = (gw > 0)     ? warped[base-1] : 0.f;
    float cr = (gw+4 < W_)  ? warped[base+4] : 0.f;
    float fl = (gw > 0)     ? fix[base-1] : 0.f;
    float fr = (gw+4 < W_)  ? fix[base+4] : 0.f;
    F4 hu;  hu.v  = (gh < H_-1) ? w4p[i4 + W_/4] : c.v;
    F4 hd;  hd.v  = (gh > 0)    ? w4p[i4 - W_/4] : c.v;
    F4 du;  du.v  = (d < D_-1)  ? w4p[i4 + HW/4] : c.v;
    F4 dn;  dn.v  = (d > 0)     ? w4p[i4 - HW/4] : c.v;
    F4 fhu; fhu.v = (gh < H_-1) ? f4p[i4 + W_/4] : fc.v;
    F4 fhd; fhd.v = (gh > 0)    ? f4p[i4 - W_/4] : fc.v;
    F4 fdu; fdu.v = (d < D_-1)  ? f4p[i4 + HW/4] : fc.v;
    F4 fdn; fdn.v = (d > 0)     ? f4p[i4 - HW/4] : fc.v;
    float hs  = (gh==0 || gh==H_-1) ? 1.f : 0.5f;
    float dsc = (d==0  || d==D_-1)  ? 1.f : 0.5f;
    if (zero_vf) {
        o0.v = zero4(); o1.v = zero4(); o2.v = zero4();
    } else {
        o0.v = ((const float4*)vf)[i4];
        o1.v = ((const float4*)vf)[i4 + N4];
        o2.v = ((const float4*)vf)[i4 + 2*N4];
    }
    float m [6] = {cl, c.a[0],  c.a[1],  c.a[2],  c.a[3],  cr};
    float fm[6] = {fl, fc.a[0], fc.a[1], fc.a[2], fc.a[3], fr};
    #pragma unroll
    for (int j = 0; j < 4; ++j) {
        int wj = gw + j;
        float wsc  = (wj == 0 || wj == W_-1) ? 1.f : 0.5f;
        float prev  = (wj == 0)    ? m[1]  : m[j];
        float next  = (wj == W_-1) ? m[4]  : m[j+2];
        float fprev = (wj == 0)    ? fm[1] : fm[j];
        float fnext = (wj == W_-1) ? fm[4] : fm[j+2];
        float G0 = dsc*(du.a[j] - dn.a[j]) + dsc*(fdu.a[j] - fdn.a[j]);
        float G1 = hs *(hu.a[j] - hd.a[j]) + hs *(fhu.a[j] - fhd.a[j]);
        float G2 = wsc*(next - prev)       + wsc*(fnext - fprev);
        float diff = c.a[j] - fc.a[j];
        float denom = G0*G0 + G1*G1 + G2*G2 + diff*diff;
        float scale = (denom > 1e-6f) ? (-diff/denom) : 0.0f;
        o0.a[j] += scale*G0;
        o1.a[j] += scale*G1;
        o2.a[j] += scale*G2;
    }
}

// ---------------------------------------------------------------------------
// Fused demons force + W-conv + H-conv for one (32x32 tile, plane d).
// Grid (5,5,128) = 3200 blocks, block (8,32); two barriers total, no loops
// over D (block-level parallelism hides latency). Output t = WH-smoothed
// force-updated field; uvf is never materialized in global memory.
// ---------------------------------------------------------------------------
__global__ __launch_bounds__(256) void force_wh_kernel(const float* __restrict__ warped,
                                                       const float* __restrict__ fix,
                                                       const float* __restrict__ vf,
                                                       float* __restrict__ tout,
                                                       int zero_vf) {
    __shared__ float u [3][36][40];   // force-updated field, rows h0-2..h0+33, cols w0-4..w0+35
    __shared__ float s1[3][36][36];   // after W-conv; cols 0..31 used (stride 36: 2-way banks)
    const int tx = threadIdx.x;       // 0..7
    const int ty = threadIdx.y;       // 0..31
    const int tid = ty*8 + tx;
    const int w0 = blockIdx.x * 32;
    const int h0 = blockIdx.y * 32;
    const int d  = blockIdx.z;

    // stage force-updated slots: 360 f4 slots (36 rows x 10 cols)
    for (int slot = tid; slot < 360; slot += 256) {
        int r = slot/10, c = slot%10;
        int gh = h0 - 2 + r;
        int gw = w0 - 4 + 4*c;
        F4 o0, o1, o2;
        if ((unsigned)gh < (unsigned)H_ && gw >= 0 && gw + 4 <= W_) {
            force_f4(warped, fix, vf, zero_vf, d, gh, gw, o0, o1, o2);
        } else {
            o0.v = zero4(); o1.v = zero4(); o2.v = zero4();
        }
        *(float4*)&u[0][r][4*c] = o0.v;
        *(float4*)&u[1][r][4*c] = o1.v;
        *(float4*)&u[2][r][4*c] = o2.v;
    }
    __syncthreads();
    // W-conv: 3ch x 36 rows x 8 f4 = 864 tasks
    for (int t = tid; t < 864; t += 256) {
        int ch = t / 288, rem = t % 288;
        int r = rem / 8, k = rem % 8;
        const float* rp = &u[ch][r][0];
        F4 a, b, cc;
        a.v  = *(const float4*)(rp + 4*k);
        b.v  = *(const float4*)(rp + 4*k + 4);
        cc.v = *(const float4*)(rp + 4*k + 8);
        float mm[12];
        #pragma unroll
        for (int j = 0; j < 4; ++j) { mm[j]=a.a[j]; mm[4+j]=b.a[j]; mm[8+j]=cc.a[j]; }
        F4 o4;
        #pragma unroll
        for (int j = 0; j < 4; ++j)
            o4.a[j] = K2*(mm[j+2]+mm[j+6]) + K1*(mm[j+3]+mm[j+5]) + K0*mm[j+4];
        *(float4*)&s1[ch][r][4*k] = o4.v;
    }
    __syncthreads();
    // H-conv + store
    size_t base = (size_t)d*HW + (h0+ty)*W_ + w0 + 4*tx;
    #pragma unroll
    for (int ch = 0; ch < 3; ++ch) {
        float4 q0 = *(const float4*)&s1[ch][ty  ][4*tx];
        float4 q1 = *(const float4*)&s1[ch][ty+1][4*tx];
        float4 q2 = *(const float4*)&s1[ch][ty+2][4*tx];
        float4 q3 = *(const float4*)&s1[ch][ty+3][4*tx];
        float4 q4 = *(const float4*)&s1[ch][ty+4][4*tx];
        float4 s2;
        s2.x = K2*(q0.x+q4.x) + K1*(q1.x+q3.x) + K0*q2.x;
        s2.y = K2*(q0.y+q4.y) + K1*(q1.y+q3.y) + K0*q2.y;
        s2.z = K2*(q0.z+q4.z) + K1*(q1.z+q3.z) + K0*q2.z;
        s2.w = K2*(q0.w+q4.w) + K1*(q1.w+q3.w) + K0*q2.w;
        *(float4*)(tout + (size_t)ch*NVOX + base) = s2;
    }
}

// ---------------------------------------------------------------------------
// D-conv (pure streaming, taps L2-resident) + trilinear warp of the result.
// One thread per spatial float4, all 3 channels. No LDS, no barriers.
// ---------------------------------------------------------------------------
__global__ __launch_bounds__(256) void smooth_d_warp_kernel(const float* __restrict__ t,
                                                            const float* __restrict__ mov,
                                                            float* __restrict__ vf_out,
                                                            float* __restrict__ warped_out,
                                                            int do_warp) {
    int i4 = blockIdx.x*blockDim.x + threadIdx.x;
    if (i4 >= N4) return;
    int base = 4*i4;
    int w = base % W_;
    int h = (base / W_) % H_;
    int d = base / HW;
    F4 va[3];
    #pragma unroll
    for (int ch = 0; ch < 3; ++ch) {
        const float4* tp = (const float4*)(t + (size_t)ch*NVOX);
        float4 q0 = (d >= 2)    ? tp[i4 - HW/2] : zero4();
        float4 q1 = (d >= 1)    ? tp[i4 - HW/4] : zero4();
        float4 q2 = tp[i4];
        float4 q3 = (d < D_-1)  ? tp[i4 + HW/4] : zero4();
        float4 q4 = (d < D_-2)  ? tp[i4 + HW/2] : zero4();
        va[ch].a[0] = K2*(q0.x+q4.x) + K1*(q1.x+q3.x) + K0*q2.x;
        va[ch].a[1] = K2*(q0.y+q4.y) + K1*(q1.y+q3.y) + K0*q2.y;
        va[ch].a[2] = K2*(q0.z+q4.z) + K1*(q1.z+q3.z) + K0*q2.z;
        va[ch].a[3] = K2*(q0.w+q4.w) + K1*(q1.w+q3.w) + K0*q2.w;
    }
    ((float4*)vf_out)[i4]        = va[0].v;
    ((float4*)vf_out)[i4 + N4]   = va[1].v;
    ((float4*)vf_out)[i4 + 2*N4] = va[2].v;
    if (do_warp) {
        F4 r4o;
        #pragma unroll
        for (int j = 0; j < 4; ++j) {
            float cd = (float)d       + va[0].a[j];
            float ch = (float)h       + va[1].a[j];
            float cw = (float)(w + j) + va[2].a[j];
            r4o.a[j] = trilerp(mov, cd, ch, cw);
        }
        ((float4*)warped_out)[i4] = r4o.v;
    }
}

extern "C" void kernel_launch(void* const* d_in, const int* in_sizes, int n_in,
                              void* d_out, int out_size, void* d_ws, size_t ws_size,
                              hipStream_t stream) {
    const float* mov = (const float*)d_in[0];
    const float* fix = (const float*)d_in[1];
    const int ITERS = 10;

    float* ws     = (float*)d_ws;
    float* vfA    = ws;                       // 3N — the vf state
    float* tbuf   = ws + (size_t)3*NVOX;      // 3N — WH-smoothed field
    float* warped = ws + (size_t)6*NVOX;      // N

    dim3 fg(W_/32, H_/32, D_);
    dim3 fb(8, 32);
    const int nb4 = (N4 + 255)/256;

    for (int it = 0; it < ITERS; ++it) {
        // it==0: vf == 0 => warped == mov exactly (integer-coordinate trilerp)
        const float* wsrc = (it == 0) ? mov : warped;
        force_wh_kernel<<<fg, fb, 0, stream>>>(wsrc, fix, vfA, tbuf, it == 0 ? 1 : 0);
        float* vdst = (it == ITERS-1) ? (float*)d_out : vfA;
        smooth_d_warp_kernel<<<nb4, 256, 0, stream>>>(tbuf, mov, vdst, warped,
                                                      it == ITERS-1 ? 0 : 1);
    }
}

// Round 8
// 733.329 us; speedup vs baseline: 1.3952x; 1.3317x over previous
//
#include <hip/hip_runtime.h>
#include <math.h>

#define D_ 128
#define H_ 160
#define W_ 160
#define NVOX (D_*H_*W_)
#define HW (H_*W_)
#define N4 (NVOX/4)

// Gaussian kernel, sigma=1, radius=2, normalized
#define K0 0.40261996f
#define K1 0.24420134f
#define K2 0.05448868f

union F4 { float4 v; float a[4]; };

__device__ __forceinline__ float4 zero4() { float4 z; z.x=z.y=z.z=z.w=0.f; return z; }

__device__ __forceinline__ float fetch_mov(const float* __restrict__ m, int d, int h, int w) {
    if ((unsigned)d >= (unsigned)D_ || (unsigned)h >= (unsigned)H_ || (unsigned)w >= (unsigned)W_) return 0.0f;
    return m[(size_t)(d*H_ + h)*W_ + w];
}

__device__ __forceinline__ float trilerp(const float* __restrict__ mov,
                                         float cd, float ch, float cw) {
    float fd = floorf(cd), fh = floorf(ch), fw = floorf(cw);
    int di = (int)fd, hi = (int)fh, wi = (int)fw;
    float td = cd - fd, th = ch - fh, tw = cw - fw;
    float c000, c001, c010, c011, c100, c101, c110, c111;
    if (di >= 0 && di < D_-1 && hi >= 0 && hi < H_-1 && wi >= 0 && wi < W_-1) {
        const float* p = mov + (size_t)di*HW + hi*W_ + wi;
        c000 = p[0];    c001 = p[1];
        c010 = p[W_];   c011 = p[W_+1];
        const float* q = p + HW;
        c100 = q[0];    c101 = q[1];
        c110 = q[W_];   c111 = q[W_+1];
    } else {
        c000 = fetch_mov(mov, di,   hi,   wi  );
        c001 = fetch_mov(mov, di,   hi,   wi+1);
        c010 = fetch_mov(mov, di,   hi+1, wi  );
        c011 = fetch_mov(mov, di,   hi+1, wi+1);
        c100 = fetch_mov(mov, di+1, hi,   wi  );
        c101 = fetch_mov(mov, di+1, hi,   wi+1);
        c110 = fetch_mov(mov, di+1, hi+1, wi  );
        c111 = fetch_mov(mov, di+1, hi+1, wi+1);
    }
    float c00 = c000 + tw*(c001 - c000);
    float c01 = c010 + tw*(c011 - c010);
    float c10 = c100 + tw*(c101 - c100);
    float c11 = c110 + tw*(c111 - c110);
    float c0 = c00 + th*(c01 - c00);
    float c1 = c10 + th*(c11 - c10);
    return c0 + td*(c1 - c0);
}

// demons force at an aligned float4 (d, gh, gw..gw+3), all inside the volume.
// Edge rule: substituting the center for a missing d/h neighbor turns the
// 0.5x central difference into the 1x one-sided difference (with hs/ds=1).
__device__ __forceinline__ void force_f4(const float* __restrict__ warped,
                                         const float* __restrict__ fix,
                                         const float* __restrict__ vf,
                                         int zero_vf, int d, int gh, int gw,
                                         F4& o0, F4& o1, F4& o2) {
    size_t base = (size_t)d*HW + gh*W_ + gw;
    int i4 = (int)(base >> 2);
    const float4* w4p = (const float4*)warped;
    const float4* f4p = (const float4*)fix;
    F4 c;  c.v  = w4p[i4];
    F4 fc; fc.v = f4p[i4];
    float cl = (gw > 0)     ? warped[base-1] : 0.f;
    float cr = (gw+4 < W_)  ? warped[base+4] : 0.f;
    float fl = (gw > 0)     ? fix[base-1] : 0.f;
    float fr = (gw+4 < W_)  ? fix[base+4] : 0.f;
    F4 hu;  hu.v  = (gh < H_-1) ? w4p[i4 + W_/4] : c.v;
    F4 hd;  hd.v  = (gh > 0)    ? w4p[i4 - W_/4] : c.v;
    F4 du;  du.v  = (d < D_-1)  ? w4p[i4 + HW/4] : c.v;
    F4 dn;  dn.v  = (d > 0)     ? w4p[i4 - HW/4] : c.v;
    F4 fhu; fhu.v = (gh < H_-1) ? f4p[i4 + W_/4] : fc.v;
    F4 fhd; fhd.v = (gh > 0)    ? f4p[i4 - W_/4] : fc.v;
    F4 fdu; fdu.v = (d < D_-1)  ? f4p[i4 + HW/4] : fc.v;
    F4 fdn; fdn.v = (d > 0)     ? f4p[i4 - HW/4] : fc.v;
    float hs  = (gh==0 || gh==H_-1) ? 1.f : 0.5f;
    float dsc = (d==0  || d==D_-1)  ? 1.f : 0.5f;
    if (zero_vf) {
        o0.v = zero4(); o1.v = zero4(); o2.v = zero4();
    } else {
        o0.v = ((const float4*)vf)[i4];
        o1.v = ((const float4*)vf)[i4 + N4];
        o2.v = ((const float4*)vf)[i4 + 2*N4];
    }
    float m [6] = {cl, c.a[0],  c.a[1],  c.a[2],  c.a[3],  cr};
    float fm[6] = {fl, fc.a[0], fc.a[1], fc.a[2], fc.a[3], fr};
    #pragma unroll
    for (int j = 0; j < 4; ++j) {
        int wj = gw + j;
        float wsc  = (wj == 0 || wj == W_-1) ? 1.f : 0.5f;
        float prev  = (wj == 0)    ? m[1]  : m[j];
        float next  = (wj == W_-1) ? m[4]  : m[j+2];
        float fprev = (wj == 0)    ? fm[1] : fm[j];
        float fnext = (wj == W_-1) ? fm[4] : fm[j+2];
        float G0 = dsc*(du.a[j] - dn.a[j]) + dsc*(fdu.a[j] - fdn.a[j]);
        float G1 = hs *(hu.a[j] - hd.a[j]) + hs *(fhu.a[j] - fhd.a[j]);
        float G2 = wsc*(next - prev)       + wsc*(fnext - fprev);
        float diff = c.a[j] - fc.a[j];
        float denom = G0*G0 + G1*G1 + G2*G2 + diff*diff;
        float scale = (denom > 1e-6f) ? (-diff/denom) : 0.0f;
        o0.a[j] += scale*G0;
        o1.a[j] += scale*G1;
        o2.a[j] += scale*G2;
    }
}

// ---------------------------------------------------------------------------
// Fused demons force + W-conv + H-conv for one (32x32 tile, plane d).
// 1D grid of 3200 blocks, XCD-swizzled: assuming round-robin dispatch
// (XCD = blockIdx % 8), XCD k owns tiles [k*400, (k+1)*400) = a contiguous
// 16-plane d-slab, so the d+-1 stencil taps of warped/fix stay in the local
// XCD L2 instead of being re-fetched from HBM by all 8 XCDs.
// ---------------------------------------------------------------------------
__global__ __launch_bounds__(256) void force_wh_kernel(const float* __restrict__ warped,
                                                       const float* __restrict__ fix,
                                                       const float* __restrict__ vf,
                                                       float* __restrict__ tout,
                                                       int zero_vf) {
    __shared__ float u [3][36][40];   // force-updated field, rows h0-2..h0+33, cols w0-4..w0+35
    __shared__ float s1[3][36][36];   // after W-conv; cols 0..31 used
    const int tx = threadIdx.x;       // 0..7
    const int ty = threadIdx.y;       // 0..31
    const int tid = ty*8 + tx;
    const int bswz = (blockIdx.x & 7)*400 + (blockIdx.x >> 3);
    const int d   = bswz / 25;
    const int rem = bswz % 25;
    const int h0 = (rem / 5) * 32;
    const int w0 = (rem % 5) * 32;

    // stage force-updated slots: 360 f4 slots (36 rows x 10 cols)
    for (int slot = tid; slot < 360; slot += 256) {
        int r = slot/10, c = slot%10;
        int gh = h0 - 2 + r;
        int gw = w0 - 4 + 4*c;
        F4 o0, o1, o2;
        if ((unsigned)gh < (unsigned)H_ && gw >= 0 && gw + 4 <= W_) {
            force_f4(warped, fix, vf, zero_vf, d, gh, gw, o0, o1, o2);
        } else {
            o0.v = zero4(); o1.v = zero4(); o2.v = zero4();
        }
        *(float4*)&u[0][r][4*c] = o0.v;
        *(float4*)&u[1][r][4*c] = o1.v;
        *(float4*)&u[2][r][4*c] = o2.v;
    }
    __syncthreads();
    // W-conv: 3ch x 36 rows x 8 f4 = 864 tasks
    for (int t = tid; t < 864; t += 256) {
        int ch = t / 288, rem2 = t % 288;
        int r = rem2 / 8, k = rem2 % 8;
        const float* rp = &u[ch][r][0];
        F4 a, b, cc;
        a.v  = *(const float4*)(rp + 4*k);
        b.v  = *(const float4*)(rp + 4*k + 4);
        cc.v = *(const float4*)(rp + 4*k + 8);
        float mm[12];
        #pragma unroll
        for (int j = 0; j < 4; ++j) { mm[j]=a.a[j]; mm[4+j]=b.a[j]; mm[8+j]=cc.a[j]; }
        F4 o4;
        #pragma unroll
        for (int j = 0; j < 4; ++j)
            o4.a[j] = K2*(mm[j+2]+mm[j+6]) + K1*(mm[j+3]+mm[j+5]) + K0*mm[j+4];
        *(float4*)&s1[ch][r][4*k] = o4.v;
    }
    __syncthreads();
    // H-conv + store
    size_t base = (size_t)d*HW + (h0+ty)*W_ + w0 + 4*tx;
    #pragma unroll
    for (int ch = 0; ch < 3; ++ch) {
        float4 q0 = *(const float4*)&s1[ch][ty  ][4*tx];
        float4 q1 = *(const float4*)&s1[ch][ty+1][4*tx];
        float4 q2 = *(const float4*)&s1[ch][ty+2][4*tx];
        float4 q3 = *(const float4*)&s1[ch][ty+3][4*tx];
        float4 q4 = *(const float4*)&s1[ch][ty+4][4*tx];
        float4 s2;
        s2.x = K2*(q0.x+q4.x) + K1*(q1.x+q3.x) + K0*q2.x;
        s2.y = K2*(q0.y+q4.y) + K1*(q1.y+q3.y) + K0*q2.y;
        s2.z = K2*(q0.z+q4.z) + K1*(q1.z+q3.z) + K0*q2.z;
        s2.w = K2*(q0.w+q4.w) + K1*(q1.w+q3.w) + K0*q2.w;
        *(float4*)(tout + (size_t)ch*NVOX + base) = s2;
    }
}

// ---------------------------------------------------------------------------
// D-conv (streaming, taps local-XCD-L2-resident via swizzle) + trilinear warp.
// One thread per spatial float4, all 3 channels. No LDS, no barriers.
// 1D grid 3200 blocks, XCD-swizzled to contiguous 16-plane slabs.
// ---------------------------------------------------------------------------
__global__ __launch_bounds__(256) void smooth_d_warp_kernel(const float* __restrict__ t,
                                                            const float* __restrict__ mov,
                                                            float* __restrict__ vf_out,
                                                            float* __restrict__ warped_out,
                                                            int do_warp) {
    const int chunk = (blockIdx.x & 7)*400 + (blockIdx.x >> 3);
    int i4 = chunk*256 + (int)threadIdx.x;
    if (i4 >= N4) return;
    int base = 4*i4;
    int w = base % W_;
    int h = (base / W_) % H_;
    int d = base / HW;
    F4 va[3];
    #pragma unroll
    for (int ch = 0; ch < 3; ++ch) {
        const float4* tp = (const float4*)(t + (size_t)ch*NVOX);
        float4 q0 = (d >= 2)    ? tp[i4 - HW/2] : zero4();
        float4 q1 = (d >= 1)    ? tp[i4 - HW/4] : zero4();
        float4 q2 = tp[i4];
        float4 q3 = (d < D_-1)  ? tp[i4 + HW/4] : zero4();
        float4 q4 = (d < D_-2)  ? tp[i4 + HW/2] : zero4();
        va[ch].a[0] = K2*(q0.x+q4.x) + K1*(q1.x+q3.x) + K0*q2.x;
        va[ch].a[1] = K2*(q0.y+q4.y) + K1*(q1.y+q3.y) + K0*q2.y;
        va[ch].a[2] = K2*(q0.z+q4.z) + K1*(q1.z+q3.z) + K0*q2.z;
        va[ch].a[3] = K2*(q0.w+q4.w) + K1*(q1.w+q3.w) + K0*q2.w;
    }
    ((float4*)vf_out)[i4]        = va[0].v;
    ((float4*)vf_out)[i4 + N4]   = va[1].v;
    ((float4*)vf_out)[i4 + 2*N4] = va[2].v;
    if (do_warp) {
        F4 r4o;
        #pragma unroll
        for (int j = 0; j < 4; ++j) {
            float cd = (float)d       + va[0].a[j];
            float ch = (float)h       + va[1].a[j];
            float cw = (float)(w + j) + va[2].a[j];
            r4o.a[j] = trilerp(mov, cd, ch, cw);
        }
        ((float4*)warped_out)[i4] = r4o.v;
    }
}

extern "C" void kernel_launch(void* const* d_in, const int* in_sizes, int n_in,
                              void* d_out, int out_size, void* d_ws, size_t ws_size,
                              hipStream_t stream) {
    const float* mov = (const float*)d_in[0];
    const float* fix = (const float*)d_in[1];
    const int ITERS = 10;

    float* ws     = (float*)d_ws;
    float* vfA    = ws;                       // 3N — the vf state
    float* tbuf   = ws + (size_t)3*NVOX;      // 3N — WH-smoothed field
    float* warped = ws + (size_t)6*NVOX;      // N

    const int nblk = 3200;   // == 5*5*128 tiles == N4/256 chunks

    for (int it = 0; it < ITERS; ++it) {
        // it==0: vf == 0 => warped == mov exactly (integer-coordinate trilerp)
        const float* wsrc = (it == 0) ? mov : warped;
        force_wh_kernel<<<dim3(nblk), dim3(8,32), 0, stream>>>(wsrc, fix, vfA, tbuf,
                                                               it == 0 ? 1 : 0);
        float* vdst = (it == ITERS-1) ? (float*)d_out : vfA;
        smooth_d_warp_kernel<<<dim3(nblk), dim3(256), 0, stream>>>(tbuf, mov, vdst, warped,
                                                                   it == ITERS-1 ? 0 : 1);
    }
}